// Round 2
// baseline (503.551 us; speedup 1.0000x reference)
//
#include <hip/hip_runtime.h>
#include <hip/hip_bf16.h>
#include <math.h>

// Problem constants (from reference)
#define NV    2048      // N
#define TT    128       // T tokens
#define TM1   127       // T-1 tensions
#define KK    20        // K = int(2048*0.01)
#define LRC   0.01f
#define EPSC  1e-8f

// Workspace layout (bytes):
//   0        int   act_idx[128*64]     (32768)
//   32768    int   act_cnt[128]        (512)
//   33280    int   occCnt[2048]        (8192)
//   41472    u8    occList[2048*128]   (262144)
//   303616   f32   ST0[2048*2048]      (16777216)   sigma transposed
// total 17,080,832 B

// ---------------------------------------------------------------------------
// Kernel 1: per-token exact top-K threshold + activation index lists +
//           per-column occurrence lists (occ[j] = steps t where j active)
// ---------------------------------------------------------------------------
__global__ __launch_bounds__(256) void act_kernel(
    const int* __restrict__ tokens, const float* __restrict__ proj,
    int* __restrict__ act_idx, int* __restrict__ act_cnt,
    int* __restrict__ occCnt, unsigned char* __restrict__ occList)
{
    const int t    = blockIdx.x;       // 0..127
    const int tid  = threadIdx.x;      // 0..255
    const int lane = tid & 63;
    const int wid  = tid >> 6;

    const float* __restrict__ row = proj + (size_t)tokens[t] * (size_t)NV;

    float v[8];
    #pragma unroll
    for (int r = 0; r < 8; ++r) v[r] = row[r * 256 + tid];   // coalesced

    __shared__ float wmax[4];
    __shared__ float gmaxS;
    __shared__ int   winner;

    float thr = 0.0f;
    // Extract the 20 largest one at a time; thr ends as the 20th largest.
    for (int it = 0; it < KK; ++it) {
        __syncthreads();
        float lm = v[0];
        #pragma unroll
        for (int r = 1; r < 8; ++r) lm = fmaxf(lm, v[r]);
        #pragma unroll
        for (int off = 32; off; off >>= 1) lm = fmaxf(lm, __shfl_down(lm, off));
        if (lane == 0) wmax[wid] = lm;
        __syncthreads();
        if (tid == 0) {
            gmaxS  = fmaxf(fmaxf(wmax[0], wmax[1]), fmaxf(wmax[2], wmax[3]));
            winner = 0x7fffffff;
        }
        __syncthreads();
        const float gm = gmaxS;
        int cand = 0x7fffffff;
        #pragma unroll
        for (int r = 0; r < 8; ++r)
            if (cand == 0x7fffffff && v[r] == gm) cand = tid * 8 + r;
        if (cand != 0x7fffffff) atomicMin(&winner, cand);
        __syncthreads();
        const int wn = winner;
        if ((wn >> 3) == tid) v[wn & 7] = -__builtin_inff();  // kill one instance
        thr = gm;
    }

    // Deterministic ordered compaction of indices with row[i] >= thr (wave 0).
    __shared__ int idxLDS[64];
    __shared__ int cntS;
    __syncthreads();
    if (wid == 0) {
        int base = 0;
        for (int round = 0; round < NV / 64; ++round) {
            const int i = round * 64 + lane;
            const bool p = (row[i] >= thr);
            const unsigned long long m = __ballot(p);
            const int pos = base + (int)__popcll(m & ((1ull << lane) - 1ull));
            if (p && pos < 64) idxLDS[pos] = i;
            base += (int)__popcll(m);
        }
        if (lane == 0) cntS = base < 64 ? base : 64;
    }
    __syncthreads();
    const int cnt = cntS;
    if (tid == 0) act_cnt[t] = cnt;
    if (tid < cnt) {
        const int j = idxLDS[tid];
        act_idx[t * 64 + tid] = j;
        const int slot = atomicAdd(&occCnt[j], 1);
        occList[j * 128 + slot] = (unsigned char)t;
    }
}

// ---------------------------------------------------------------------------
// Kernel 2: ST0[j][i] = sigma[i][j]  (so column gathers become coalesced rows)
// ---------------------------------------------------------------------------
__global__ __launch_bounds__(256) void transpose_kernel(
    const float* __restrict__ in, float* __restrict__ out)
{
    __shared__ float tile[32][33];
    const int tx = threadIdx.x;       // 0..31
    const int ty = threadIdx.y;       // 0..7
    const int x0 = blockIdx.x * 32;
    const int y0 = blockIdx.y * 32;
    #pragma unroll
    for (int k = 0; k < 4; ++k)
        tile[ty + k * 8][tx] = in[(size_t)(y0 + ty + k * 8) * NV + x0 + tx];
    __syncthreads();
    #pragma unroll
    for (int k = 0; k < 4; ++k)
        out[(size_t)(x0 + ty + k * 8) * NV + y0 + tx] = tile[tx][ty + k * 8];
}

// ---------------------------------------------------------------------------
// Kernel 3: one block per step t (0..126), all steps independent.
//   pred[i] = sum_{j in A_t} min(1, sigma0[i][j] + LR*c_t(i,j))
//   c_t(i,j) = #{s < t : j in A_s, i in A_{s+1}}
// ---------------------------------------------------------------------------
__global__ __launch_bounds__(512) void tension_kernel(
    const float* __restrict__ sigma0, const float* __restrict__ ST0,
    const int* __restrict__ act_idx, const int* __restrict__ act_cnt,
    const int* __restrict__ occCnt, const unsigned char* __restrict__ occList,
    const int* __restrict__ plast, float* __restrict__ out)
{
    const int t    = blockIdx.x;       // 0..126
    const int tid  = threadIdx.x;      // 0..511
    const int lane = tid & 63;
    const int wid  = tid >> 6;

    __shared__ float          predS[NV];
    __shared__ float          deltaS[NV];
    __shared__ unsigned int   cnt[NV];
    __shared__ unsigned short list[NV];
    __shared__ unsigned int   listCnt;
    __shared__ int            acur[64], anext[64];
    __shared__ float          wsum[8];

    const int ccur  = act_cnt[t];
    const int cnext = act_cnt[t + 1];
    if (tid < 64) {
        acur[tid]  = act_idx[t * 64 + tid];
        anext[tid] = act_idx[(t + 1) * 64 + tid];
    }
    for (int i = tid; i < NV; i += 512) { deltaS[i] = 0.0f; cnt[i] = 0u; }
    if (tid == 0) listCnt = 0u;
    __syncthreads();

    // Base pred from original sigma: coalesced row reads of ST0.
    float acc[4] = {0.f, 0.f, 0.f, 0.f};
    for (int jj = 0; jj < ccur; ++jj) {
        const float* __restrict__ rowp = ST0 + (size_t)acur[jj] * NV;
        #pragma unroll
        for (int r = 0; r < 4; ++r) acc[r] += rowp[r * 512 + tid];
    }

    const bool plas = (plast[0] != 0);
    if (plas) {
        for (int jj = 0; jj < ccur; ++jj) {
            const int j  = acur[jj];
            const int oc = occCnt[j];
            // accumulate counts c(i,j) over prior steps s<t with j in A_s
            for (int p = tid; p < oc * 64; p += 512) {
                const int o  = p >> 6;
                const int ii = p & 63;
                const int s  = (int)occList[j * 128 + o];
                if (s < t) {
                    const int cs = act_cnt[s + 1];
                    if (ii < cs) {
                        const int i = act_idx[(s + 1) * 64 + ii];
                        const unsigned old = atomicAdd(&cnt[i], 1u);
                        if (old == 0u) {
                            const unsigned pos = atomicAdd(&listCnt, 1u);
                            list[pos] = (unsigned short)i;
                        }
                    }
                }
            }
            __syncthreads();
            const unsigned L = listCnt;
            __syncthreads();
            for (unsigned e = tid; e < L; e += 512) {
                const int i = (int)list[e];
                const unsigned c = cnt[i];
                const float s0 = sigma0[(size_t)i * NV + j];
                deltaS[i] += fminf(1.0f - s0, LRC * (float)c);  // clipped delta
                cnt[i] = 0u;
            }
            if (tid == 0) listCnt = 0u;
            __syncthreads();
        }
    }

    // Final pred into LDS
    #pragma unroll
    for (int r = 0; r < 4; ++r) {
        const int i = r * 512 + tid;
        predS[i] = acc[r] + deltaS[i];
    }
    __syncthreads();

    // norm^2 reduce over all 2048
    float loc = 0.0f;
    #pragma unroll
    for (int r = 0; r < 4; ++r) { const float p = predS[r * 512 + tid]; loc += p * p; }
    #pragma unroll
    for (int off = 32; off; off >>= 1) loc += __shfl_down(loc, off);
    if (lane == 0) wsum[wid] = loc;
    __syncthreads();

    if (tid < 64) {
        float n2 = 0.0f;
        #pragma unroll
        for (int w = 0; w < 8; ++w) n2 += wsum[w];
        float d = (tid < cnext) ? predS[anext[tid]] : 0.0f;
        #pragma unroll
        for (int off = 32; off; off >>= 1) d += __shfl_down(d, off);
        if (tid == 0) {
            const float pn = sqrtf(n2);
            float tens;
            if (plas) {
                const float overlap = d / (pn * sqrtf((float)KK) + EPSC);
                tens = (pn > 0.0f) ? (1.0f - overlap) : 1.0f;
            } else {
                const float overlap = d / (pn * sqrtf((float)cnext) + EPSC);
                tens = 1.0f - overlap;
            }
            out[t] = tens;
        }
    }
}

// ---------------------------------------------------------------------------
extern "C" void kernel_launch(void* const* d_in, const int* in_sizes, int n_in,
                              void* d_out, int out_size, void* d_ws, size_t ws_size,
                              hipStream_t stream)
{
    const int*   tokens = (const int*)d_in[0];
    const float* proj   = (const float*)d_in[1];
    const float* sigma  = (const float*)d_in[2];
    const int*   plast  = (const int*)d_in[3];
    float*       out    = (float*)d_out;

    char* ws = (char*)d_ws;
    int*           act_idx = (int*)(ws + 0);
    int*           act_cnt = (int*)(ws + 32768);
    int*           occCnt  = (int*)(ws + 33280);
    unsigned char* occList = (unsigned char*)(ws + 41472);
    float*         ST0     = (float*)(ws + 303616);

    hipMemsetAsync(occCnt, 0, NV * sizeof(int), stream);
    act_kernel<<<TT, 256, 0, stream>>>(tokens, proj, act_idx, act_cnt, occCnt, occList);
    transpose_kernel<<<dim3(NV / 32, NV / 32), dim3(32, 8), 0, stream>>>(sigma, ST0);
    tension_kernel<<<TM1, 512, 0, stream>>>(sigma, ST0, act_idx, act_cnt, occCnt,
                                            occList, plast, out);
}